// Round 20
// baseline (117.937 us; speedup 1.0000x reference)
//
#include <hip/hip_runtime.h>

typedef __attribute__((ext_vector_type(8))) short short8;
typedef __attribute__((ext_vector_type(4))) float f32x4;
typedef __attribute__((ext_vector_type(16))) float f32x16;
typedef __attribute__((ext_vector_type(4))) unsigned short ushort4v;

#define HIDDEN 1024
#define NHEAD 16
#define HD 64
#define BATCH 2
#define SEQ 2048
#define MROWS (BATCH * SEQ)  // 4096
// 0.125 * log2(e): QK^T scores land in log2 domain -> softmax uses bare v_exp_f32
#define QSCALE 0.18033688011112042f

__device__ __forceinline__ unsigned short f2b(float f) {
  union { float f; unsigned u; } v; v.f = f;
  unsigned r = v.u + 0x7fffu + ((v.u >> 16) & 1u);
  return (unsigned short)(r >> 16);
}

__device__ __forceinline__ unsigned cvt_pk_bf16(float lo, float hi) {
  unsigned r;
  asm("v_cvt_pk_bf16_f32 %0, %1, %2" : "=v"(r) : "v"(lo), "v"(hi));
  return r;
}

__device__ __forceinline__ float fexp2(float x) {
#if __has_builtin(__builtin_amdgcn_exp2f)
  return __builtin_amdgcn_exp2f(x);
#else
  return exp2f(x);
#endif
}

// async global->LDS, 16B per lane; LDS dest = wave-uniform base + lane*16
__device__ __forceinline__ void gll16(const void* g, void* l) {
  __builtin_amdgcn_global_load_lds(
      (__attribute__((address_space(1))) void*)g,
      (__attribute__((address_space(3))) void*)l, 16, 0, 0);
}

// ---------------- merged f32 -> bf16 conversions (x + 4 weights) ----------------
__global__ void prep_kernel(const float* __restrict__ x,
                            const float* __restrict__ Wq,
                            const float* __restrict__ Wk,
                            const float* __restrict__ Wv,
                            const float* __restrict__ Wo,
                            unsigned short* __restrict__ xb,
                            unsigned short* __restrict__ wqb,
                            unsigned short* __restrict__ wkb,
                            unsigned short* __restrict__ wvb,
                            unsigned short* __restrict__ wob) {
  int bid = blockIdx.x;
  const float* src;
  unsigned short* dst;
  int base;
  if (bid < 4096)      { src = x;  dst = xb;  base = bid; }
  else if (bid < 5120) { src = Wq; dst = wqb; base = bid - 4096; }
  else if (bid < 6144) { src = Wk; dst = wkb; base = bid - 5120; }
  else if (bid < 7168) { src = Wv; dst = wvb; base = bid - 6144; }
  else                 { src = Wo; dst = wob; base = bid - 7168; }
  int i = (base * 256 + threadIdx.x) * 4;
  float4 v = *reinterpret_cast<const float4*>(src + i);
  ushort4v o;
  o.x = f2b(v.x); o.y = f2b(v.y); o.z = f2b(v.z); o.w = f2b(v.w);
  *reinterpret_cast<ushort4v*>(dst + i) = o;
}

// ---------------- fused QKV GEMM: 64x128 tile, BK=64, 2-phase dbuf -----------
// N=3072; region = n0>>10 selects W0/W1/W2; writes q (scaled), k, v^T.
// 48 KB LDS -> 3 blocks/CU; grid (64,24) = 1536 = exactly 2 occupancy rounds.
__global__ __launch_bounds__(256) void gemm_qkv_kernel(
    const unsigned short* __restrict__ A,
    const unsigned short* __restrict__ W0,
    const unsigned short* __restrict__ W1,
    const unsigned short* __restrict__ W2,
    const float* __restrict__ c0, const float* __restrict__ c1,
    const float* __restrict__ c2, void* __restrict__ o0,
    void* __restrict__ o1, void* __restrict__ o2) {
  __shared__ __align__(16) unsigned short Al[2][64 * 64];
  __shared__ __align__(16) unsigned short Bl[2][128 * 64];
  const int t = threadIdx.x;
  const int w = t >> 6, l = t & 63;
  const int hi = l >> 4, lo16 = l & 15;
  const int m0 = blockIdx.x * 64;
  const int n0 = blockIdx.y * 128;
  const int K = HIDDEN;

  const int region = n0 >> 10;
  const int n_loc = n0 & 1023;
  const unsigned short* Bsel = region == 0 ? W0 : (region == 1 ? W1 : W2);
  const float* bias = region == 0 ? c0 : (region == 1 ? c1 : c2);

  const int schunk = (l & 7) ^ (l >> 3);
  const int rsw = (lo16 & 7);

  const unsigned short* pA[2];
#pragma unroll
  for (int i = 0; i < 2; ++i)
    pA[i] = A + (size_t)(m0 + w * 16 + i * 8 + (l >> 3)) * K + schunk * 8;
  const unsigned short* pB[4];
#pragma unroll
  for (int i = 0; i < 4; ++i)
    pB[i] = Bsel + (size_t)(n_loc + w * 32 + i * 8 + (l >> 3)) * K + schunk * 8;

  f32x4 acc[4][2];
#pragma unroll
  for (int mi = 0; mi < 4; ++mi)
#pragma unroll
    for (int f = 0; f < 2; ++f) acc[mi][f] = f32x4{0.f, 0.f, 0.f, 0.f};

  auto stage = [&](int BUF) __attribute__((always_inline)) {
#pragma unroll
    for (int i = 0; i < 2; ++i) {
      gll16(pA[i], &Al[BUF][(w * 16 + i * 8) * 64]);
      pA[i] += 64;
    }
#pragma unroll
    for (int i = 0; i < 4; ++i) {
      gll16(pB[i], &Bl[BUF][(w * 32 + i * 8) * 64]);
      pB[i] += 64;
    }
  };

  stage(0);
  __syncthreads();

  auto step = [&](int knext, int BUF) __attribute__((always_inline)) {
    if (knext < K) stage(BUF ^ 1);
#pragma unroll
    for (int kk = 0; kk < 2; ++kk) {
      short8 af[4], bf[2];
#pragma unroll
      for (int mi = 0; mi < 4; ++mi)
        af[mi] = *reinterpret_cast<const short8*>(
            &Al[BUF][(mi * 16 + lo16) * 64 + (((kk * 4 + hi) ^ rsw) * 8)]);
#pragma unroll
      for (int f = 0; f < 2; ++f)
        bf[f] = *reinterpret_cast<const short8*>(
            &Bl[BUF][(w * 32 + f * 16 + lo16) * 64 + (((kk * 4 + hi) ^ rsw) * 8)]);
#pragma unroll
      for (int mi = 0; mi < 4; ++mi)
#pragma unroll
        for (int f = 0; f < 2; ++f)
          acc[mi][f] =
              __builtin_amdgcn_mfma_f32_16x16x32_bf16(af[mi], bf[f], acc[mi][f], 0, 0, 0);
    }
    __syncthreads();
  };

  for (int kt = 0; kt < K; kt += 128) {
    step(kt + 64, 0);
    step(kt + 128, 1);
  }

#pragma unroll
  for (int mi = 0; mi < 4; ++mi)
#pragma unroll
    for (int f = 0; f < 2; ++f) {
      int mbase = m0 + mi * 16 + hi * 4;
      int n_rel = n_loc + w * 32 + f * 16 + lo16;
      float bv_ = bias[n_rel];
      if (region == 2) {
        // V^T: 4 consecutive s for fixed d -> one packed 8B store
        int b = mbase >> 11, s = mbase & 2047, d = n_rel & 63, h = n_rel >> 6;
        uint2 pk;
        pk.x = cvt_pk_bf16(acc[mi][f][0] + bv_, acc[mi][f][1] + bv_);
        pk.y = cvt_pk_bf16(acc[mi][f][2] + bv_, acc[mi][f][3] + bv_);
        *reinterpret_cast<uint2*>(
            (unsigned short*)o2 + ((size_t)(b * NHEAD + h) * HD + d) * SEQ + s) = pk;
        continue;
      }
#pragma unroll
      for (int j = 0; j < 4; ++j) {
        float v = acc[mi][f][j] + bv_;
        int mm = mbase + j;
        int b = mm >> 11, s = mm & 2047, h = n_rel >> 6, d = n_rel & 63;
        if (region == 0)
          ((unsigned short*)o0)[((size_t)(b * NHEAD + h) * SEQ + s) * HD + d] =
              f2b(v * QSCALE);
        else
          ((unsigned short*)o1)[((size_t)(b * NHEAD + h) * SEQ + s) * HD + d] =
              f2b(v);
      }
    }
}

// ---------------- O-projection GEMM: 64x128 tile, BK=64, 2-phase dbuf --------
// (exact R18 kernel: proven ~13 us)
__global__ __launch_bounds__(256) void gemm_o_kernel(
    const unsigned short* __restrict__ A, const unsigned short* __restrict__ W0,
    const float* __restrict__ bias, float* __restrict__ out) {
  __shared__ __align__(16) unsigned short Al[2][64 * 64];
  __shared__ __align__(16) unsigned short Bl[2][128 * 64];
  const int t = threadIdx.x;
  const int w = t >> 6, l = t & 63;
  const int hi = l >> 4, lo16 = l & 15;
  const int m0 = blockIdx.x * 64;
  const int n0 = blockIdx.y * 128;
  const int K = HIDDEN;

  const int schunk = (l & 7) ^ (l >> 3);
  const int rsw = (lo16 & 7);

  const unsigned short* pA[2];
#pragma unroll
  for (int i = 0; i < 2; ++i)
    pA[i] = A + (size_t)(m0 + w * 16 + i * 8 + (l >> 3)) * K + schunk * 8;
  const unsigned short* pB[4];
#pragma unroll
  for (int i = 0; i < 4; ++i)
    pB[i] = W0 + (size_t)(n0 + w * 32 + i * 8 + (l >> 3)) * K + schunk * 8;

  f32x4 acc[4][2];
#pragma unroll
  for (int mi = 0; mi < 4; ++mi)
#pragma unroll
    for (int f = 0; f < 2; ++f) acc[mi][f] = f32x4{0.f, 0.f, 0.f, 0.f};

  auto stage = [&](int BUF) __attribute__((always_inline)) {
#pragma unroll
    for (int i = 0; i < 2; ++i) {
      gll16(pA[i], &Al[BUF][(w * 16 + i * 8) * 64]);
      pA[i] += 64;
    }
#pragma unroll
    for (int i = 0; i < 4; ++i) {
      gll16(pB[i], &Bl[BUF][(w * 32 + i * 8) * 64]);
      pB[i] += 64;
    }
  };

  stage(0);
  __syncthreads();

  auto step = [&](int knext, int BUF) __attribute__((always_inline)) {
    if (knext < K) stage(BUF ^ 1);
#pragma unroll
    for (int kk = 0; kk < 2; ++kk) {
      short8 af[4], bf[2];
#pragma unroll
      for (int mi = 0; mi < 4; ++mi)
        af[mi] = *reinterpret_cast<const short8*>(
            &Al[BUF][(mi * 16 + lo16) * 64 + (((kk * 4 + hi) ^ rsw) * 8)]);
#pragma unroll
      for (int f = 0; f < 2; ++f)
        bf[f] = *reinterpret_cast<const short8*>(
            &Bl[BUF][(w * 32 + f * 16 + lo16) * 64 + (((kk * 4 + hi) ^ rsw) * 8)]);
#pragma unroll
      for (int mi = 0; mi < 4; ++mi)
#pragma unroll
        for (int f = 0; f < 2; ++f)
          acc[mi][f] =
              __builtin_amdgcn_mfma_f32_16x16x32_bf16(af[mi], bf[f], acc[mi][f], 0, 0, 0);
    }
    __syncthreads();
  };

  for (int kt = 0; kt < K; kt += 128) {
    step(kt + 64, 0);
    step(kt + 128, 1);
  }

#pragma unroll
  for (int mi = 0; mi < 4; ++mi)
#pragma unroll
    for (int f = 0; f < 2; ++f) {
      int mbase = m0 + mi * 16 + hi * 4;
      int n = n0 + w * 32 + f * 16 + lo16;
      float bv_ = bias[n];
#pragma unroll
      for (int j = 0; j < 4; ++j)
        out[(size_t)(mbase + j) * HIDDEN + n] = acc[mi][f][j] + bv_;
    }
}

// ---------------- flash attention: 8 waves, k-split, ring-4, 2-stage pipe ----
// R18 kernel with the mask conversion fused: C-init reads the raw int mask
// and selects -1e30/0 inline (deletes the separate amask kernel + launch).
__global__ __launch_bounds__(512) void attn_kernel(
    const unsigned short* __restrict__ Q, const unsigned short* __restrict__ Km,
    const unsigned short* __restrict__ Vt, const int* __restrict__ mask,
    unsigned short* __restrict__ O) {
  __shared__ __align__(16) unsigned short KV[4][2][64 * 64];  // 64 KB ring
  __shared__ float SrwS[4][64];
  const int t = threadIdx.x;
  const int w = t >> 6, l = t & 63;
  const int q31 = l & 31, hi32 = l >> 5;
  const int qg = w >> 1, half = w & 1;
  const int nb = ((blockIdx.x & 7) << 6) | (blockIdx.x >> 3);
  const int qt = nb & 15, bh = nb >> 4;
  const int b = bh >> 4, h = bh & 15;
  const int q0w = qt * 128 + qg * 32;
  const int q = q0w + q31;
  const bool diagw = (half == (qg & 1));
  const int dtile = qt * 128 + (qg >> 1) * 64;

  const unsigned short* Qb = Q + (size_t)bh * SEQ * HD;
  const unsigned short* Kb = Km + (size_t)bh * SEQ * HD;
  const unsigned short* Vb = Vt + (size_t)bh * HD * SEQ;
  const int* mb = mask + b * SEQ + half * 32;

  short8 qf[4];
#pragma unroll
  for (int dc = 0; dc < 4; ++dc)
    qf[dc] = *reinterpret_cast<const short8*>(
        Qb + (size_t)q * HD + dc * 16 + hi32 * 8);

  f32x16 o0, o1;
#pragma unroll
  for (int r = 0; r < 16; ++r) { o0[r] = 0.f; o1[r] = 0.f; }
  float srw = 0.f;

  const int srow = w * 8 + (l >> 3);
  const int sc_ = ((l & 7) ^ (l >> 3) ^ (w & 3)) * 8;
  const unsigned short* pK = Kb + (size_t)srow * HD + sc_;
  const unsigned short* pV = Vb + (size_t)srow * SEQ + sc_;

  auto stageT = [&](int BUF) __attribute__((always_inline)) {
    gll16(pK, &KV[BUF][0][(w * 8) * 64]);
    gll16(pV, &KV[BUF][1][(w * 8) * 64]);
    pK += 64 * HD; pV += 64;
  };

  stageT(0);
  stageT(1);
  stageT(2);
  asm volatile("s_waitcnt vmcnt(2)" ::: "memory");
  __builtin_amdgcn_s_barrier();
  __builtin_amdgcn_sched_barrier(0);

  const int rk = (q31 & 7) ^ (q31 >> 3);

  // masked scores for tile k0 into s: C-init from int mask (inline convert),
  // diagonal exception in the one diag tile, then 4 chained MFMA.
  auto qk = [&](int k0, int BUF, f32x16& s) __attribute__((always_inline)) {
    int4 mi4[4];
#pragma unroll
    for (int g = 0; g < 4; ++g)
      mi4[g] = *reinterpret_cast<const int4*>(mb + k0 + g * 8 + hi32 * 4);
    float4 a0[4];
#pragma unroll
    for (int g = 0; g < 4; ++g) {
      a0[g].x = mi4[g].x ? -1e30f : 0.f;
      a0[g].y = mi4[g].y ? -1e30f : 0.f;
      a0[g].z = mi4[g].z ? -1e30f : 0.f;
      a0[g].w = mi4[g].w ? -1e30f : 0.f;
    }
    if (diagw && k0 == dtile) {
      int kb = hi32 * 4;
#pragma unroll
      for (int g = 0; g < 4; ++g) {
        if (kb + g * 8 + 0 == q31) a0[g].x = 0.f;
        if (kb + g * 8 + 1 == q31) a0[g].y = 0.f;
        if (kb + g * 8 + 2 == q31) a0[g].z = 0.f;
        if (kb + g * 8 + 3 == q31) a0[g].w = 0.f;
      }
    }
#pragma unroll
    for (int g = 0; g < 4; ++g) {
      s[4 * g + 0] = a0[g].x; s[4 * g + 1] = a0[g].y;
      s[4 * g + 2] = a0[g].z; s[4 * g + 3] = a0[g].w;
    }
    __builtin_amdgcn_s_setprio(1);
#pragma unroll
    for (int dc = 0; dc < 4; ++dc) {
      short8 kf = *reinterpret_cast<const short8*>(
          &KV[BUF][0][(half * 32 + q31) * 64 + (((dc * 2 + hi32) ^ rk) * 8)]);
      s = __builtin_amdgcn_mfma_f32_32x32x16_bf16(kf, qf[dc], s, 0, 0, 0);
    }
    __builtin_amdgcn_s_setprio(0);
  };

  auto spv = [&](int BUF, f32x16& s) __attribute__((always_inline)) {
    float sum = 0.f;
#pragma unroll
    for (int r = 0; r < 16; ++r) {
      float p = fexp2(s[r]);
      s[r] = p;
      sum += p;
    }
    {
      unsigned a = __float_as_uint(sum), bsw = a;
      auto rr = __builtin_amdgcn_permlane32_swap(a, bsw, false, false);
      sum = __uint_as_float(rr[0]) + __uint_as_float(rr[1]);
    }
    srw += sum;

    unsigned c[8];
#pragma unroll
    for (int R = 0; R < 4; ++R) {
      c[R * 2 + 0] = cvt_pk_bf16(s[4 * R + 0], s[4 * R + 1]);
      c[R * 2 + 1] = cvt_pk_bf16(s[4 * R + 2], s[4 * R + 3]);
    }

    short8 pb[2];
#pragma unroll
    for (int sl = 0; sl < 2; ++sl) {
      const int R0 = sl * 2;
      auto r0 = __builtin_amdgcn_permlane32_swap(c[R0 * 2 + 0],
                                                 c[(R0 + 1) * 2 + 0], false, false);
      auto r1 = __builtin_amdgcn_permlane32_swap(c[R0 * 2 + 1],
                                                 c[(R0 + 1) * 2 + 1], false, false);
      union { unsigned u[4]; short8 s8; } pu;
      pu.u[0] = r0[0]; pu.u[1] = r1[0]; pu.u[2] = r0[1]; pu.u[3] = r1[1];
      pb[sl] = pu.s8;
    }

    __builtin_amdgcn_s_setprio(1);
#pragma unroll
    for (int sl = 0; sl < 2; ++sl) {
      int ch = (((half * 2 + sl) * 2 + hi32) ^ rk) * 8;
      short8 vf0 = *reinterpret_cast<const short8*>(&KV[BUF][1][q31 * 64 + ch]);
      short8 vf1 =
          *reinterpret_cast<const short8*>(&KV[BUF][1][(32 + q31) * 64 + ch]);
      o0 = __builtin_amdgcn_mfma_f32_32x32x16_bf16(vf0, pb[sl], o0, 0, 0, 0);
      o1 = __builtin_amdgcn_mfma_f32_32x32x16_bf16(vf1, pb[sl], o1, 0, 0, 0);
    }
    __builtin_amdgcn_s_setprio(0);
  };

  f32x16 sA, sB;
  qk(0, 0, sA);

  auto pipe = [&](int k0, int BUF, int NBUF, f32x16& scur, f32x16& snext,
                  int WAITN) __attribute__((always_inline)) {
    if (k0 + 192 < SEQ) stageT(NBUF);
    if (k0 + 64 < SEQ) qk(k0 + 64, (BUF + 1) & 3, snext);
    spv(BUF, scur);
    if (WAITN == 2)
      asm volatile("s_waitcnt vmcnt(2)" ::: "memory");
    else if (WAITN == 0)
      asm volatile("s_waitcnt vmcnt(0)" ::: "memory");
    if (WAITN >= 0) {
      __builtin_amdgcn_s_barrier();
      __builtin_amdgcn_sched_barrier(0);
    }
  };

  for (int tt = 0; tt < 28; tt += 4) {
    pipe((tt + 0) * 64, 0, 3, sA, sB, 2);
    pipe((tt + 1) * 64, 1, 0, sB, sA, 2);
    pipe((tt + 2) * 64, 2, 1, sA, sB, 2);
    pipe((tt + 3) * 64, 3, 2, sB, sA, 2);
  }
  pipe(28 * 64, 0, 3, sA, sB, 2);
  pipe(29 * 64, 1, 0, sB, sA, 0);
  pipe(30 * 64, 2, 1, sA, sB, -1);
  pipe(31 * 64, 3, 2, sB, sA, -1);

  float* obuf = (float*)&KV[0][0][0];  // 33 KB, disjoint from tiles 30/31 bufs
  if (half) {
    float* d = obuf + (qg * 64 + l) * 33;
#pragma unroll
    for (int r = 0; r < 16; ++r) { d[r] = o0[r]; d[16 + r] = o1[r]; }
    SrwS[qg][l] = srw;
  }
  __syncthreads();
  if (!half) {
    const float* d = obuf + (qg * 64 + l) * 33;
#pragma unroll
    for (int r = 0; r < 16; ++r) { o0[r] += d[r]; o1[r] += d[16 + r]; }
    srw += SrwS[qg][l];

    float rinv = 1.f / srw;
    unsigned short* Ob = O + (size_t)(b * SEQ + q) * HIDDEN + h * HD;
#pragma unroll
    for (int g = 0; g < 4; ++g) {
      uint2 w0, w1;
      w0.x = cvt_pk_bf16(o0[4 * g + 0] * rinv, o0[4 * g + 1] * rinv);
      w0.y = cvt_pk_bf16(o0[4 * g + 2] * rinv, o0[4 * g + 3] * rinv);
      w1.x = cvt_pk_bf16(o1[4 * g + 0] * rinv, o1[4 * g + 1] * rinv);
      w1.y = cvt_pk_bf16(o1[4 * g + 2] * rinv, o1[4 * g + 3] * rinv);
      *reinterpret_cast<uint2*>(Ob + 8 * g + 4 * hi32) = w0;
      *reinterpret_cast<uint2*>(Ob + 32 + 8 * g + 4 * hi32) = w1;
    }
  }
}

// ---------------- launch ----------------
extern "C" void kernel_launch(void* const* d_in, const int* in_sizes, int n_in,
                              void* d_out, int out_size, void* d_ws,
                              size_t ws_size, hipStream_t stream) {
  const float* x = (const float*)d_in[0];
  const int* mask = (const int*)d_in[1];
  const float* Wq = (const float*)d_in[2];
  const float* bq = (const float*)d_in[3];
  const float* Wk = (const float*)d_in[4];
  const float* bk = (const float*)d_in[5];
  const float* Wv = (const float*)d_in[6];
  const float* bv = (const float*)d_in[7];
  const float* Wo = (const float*)d_in[8];
  const float* bo = (const float*)d_in[9];

  char* ws = (char*)d_ws;
  unsigned short* xb  = (unsigned short*)(ws + ((size_t)0 << 20));   // 8 MB
  unsigned short* wqb = (unsigned short*)(ws + ((size_t)8 << 20));   // 2 MB
  unsigned short* wkb = (unsigned short*)(ws + ((size_t)10 << 20));
  unsigned short* wvb = (unsigned short*)(ws + ((size_t)12 << 20));
  unsigned short* wob = (unsigned short*)(ws + ((size_t)14 << 20));
  unsigned short* qw  = (unsigned short*)(ws + ((size_t)16 << 20));  // 8 MB
  unsigned short* kw  = (unsigned short*)(ws + ((size_t)24 << 20));
  unsigned short* vtw = (unsigned short*)(ws + ((size_t)32 << 20));
  unsigned short* ow  = (unsigned short*)(ws + ((size_t)40 << 20));

  // all f32->bf16 conversions in one launch
  prep_kernel<<<8192, 256, 0, stream>>>(x, Wq, Wk, Wv, Wo, xb, wqb, wkb, wvb,
                                        wob);

  // fused QKV projection: [4096 x 3072], 64x128 tiles
  gemm_qkv_kernel<<<dim3(MROWS / 64, 3 * HIDDEN / 128), 256, 0, stream>>>(
      xb, wqb, wkb, wvb, bq, bk, bv, qw, kw, vtw);

  // attention (mask conversion fused into C-init)
  attn_kernel<<<512, 512, 0, stream>>>(qw, kw, vtw, mask, ow);

  // output projection: [4096 x 1024] f32, 64x128 tiles
  gemm_o_kernel<<<dim3(MROWS / 64, HIDDEN / 128), 256, 0, stream>>>(
      ow, wob, bo, (float*)d_out);
}

// Round 21
// 114.344 us; speedup vs baseline: 1.0314x; 1.0314x over previous
//
#include <hip/hip_runtime.h>

typedef __attribute__((ext_vector_type(8))) short short8;
typedef __attribute__((ext_vector_type(4))) float f32x4;
typedef __attribute__((ext_vector_type(16))) float f32x16;
typedef __attribute__((ext_vector_type(4))) unsigned short ushort4v;

#define HIDDEN 1024
#define NHEAD 16
#define HD 64
#define BATCH 2
#define SEQ 2048
#define MROWS (BATCH * SEQ)  // 4096
// 0.125 * log2(e): QK^T scores land in log2 domain -> softmax uses bare v_exp_f32
#define QSCALE 0.18033688011112042f

__device__ __forceinline__ unsigned short f2b(float f) {
  union { float f; unsigned u; } v; v.f = f;
  unsigned r = v.u + 0x7fffu + ((v.u >> 16) & 1u);
  return (unsigned short)(r >> 16);
}

__device__ __forceinline__ unsigned cvt_pk_bf16(float lo, float hi) {
  unsigned r;
  asm("v_cvt_pk_bf16_f32 %0, %1, %2" : "=v"(r) : "v"(lo), "v"(hi));
  return r;
}

__device__ __forceinline__ float fexp2(float x) {
#if __has_builtin(__builtin_amdgcn_exp2f)
  return __builtin_amdgcn_exp2f(x);
#else
  return exp2f(x);
#endif
}

// async global->LDS, 16B per lane; LDS dest = wave-uniform base + lane*16
__device__ __forceinline__ void gll16(const void* g, void* l) {
  __builtin_amdgcn_global_load_lds(
      (__attribute__((address_space(1))) void*)g,
      (__attribute__((address_space(3))) void*)l, 16, 0, 0);
}

// ---------------- merged f32 -> bf16 conversions (x + 4 weights) ----------------
__global__ void prep_kernel(const float* __restrict__ x,
                            const float* __restrict__ Wq,
                            const float* __restrict__ Wk,
                            const float* __restrict__ Wv,
                            const float* __restrict__ Wo,
                            unsigned short* __restrict__ xb,
                            unsigned short* __restrict__ wqb,
                            unsigned short* __restrict__ wkb,
                            unsigned short* __restrict__ wvb,
                            unsigned short* __restrict__ wob) {
  int bid = blockIdx.x;
  const float* src;
  unsigned short* dst;
  int base;
  if (bid < 4096)      { src = x;  dst = xb;  base = bid; }
  else if (bid < 5120) { src = Wq; dst = wqb; base = bid - 4096; }
  else if (bid < 6144) { src = Wk; dst = wkb; base = bid - 5120; }
  else if (bid < 7168) { src = Wv; dst = wvb; base = bid - 6144; }
  else                 { src = Wo; dst = wob; base = bid - 7168; }
  int i = (base * 256 + threadIdx.x) * 4;
  float4 v = *reinterpret_cast<const float4*>(src + i);
  ushort4v o;
  o.x = f2b(v.x); o.y = f2b(v.y); o.z = f2b(v.z); o.w = f2b(v.w);
  *reinterpret_cast<ushort4v*>(dst + i) = o;
}

// ---------------- mask -> additive f32 ----------------
__global__ void amask_kernel(const int* __restrict__ m, float* __restrict__ am,
                             int n) {
  int i = blockIdx.x * blockDim.x + threadIdx.x;
  if (i < n) am[i] = m[i] ? -1e30f : 0.f;
}

// ---------------- fused QKV GEMM: 64x128 tile, BK=64, 2-phase dbuf -----------
// N=3072; region = n0>>10 selects W0/W1/W2; writes q (scaled), k, v^T.
// 48 KB LDS -> 3 blocks/CU; grid (64,24) = 1536 = exactly 2 occupancy rounds.
__global__ __launch_bounds__(256) void gemm_qkv_kernel(
    const unsigned short* __restrict__ A,
    const unsigned short* __restrict__ W0,
    const unsigned short* __restrict__ W1,
    const unsigned short* __restrict__ W2,
    const float* __restrict__ c0, const float* __restrict__ c1,
    const float* __restrict__ c2, void* __restrict__ o0,
    void* __restrict__ o1, void* __restrict__ o2) {
  __shared__ __align__(16) unsigned short Al[2][64 * 64];
  __shared__ __align__(16) unsigned short Bl[2][128 * 64];
  const int t = threadIdx.x;
  const int w = t >> 6, l = t & 63;
  const int hi = l >> 4, lo16 = l & 15;
  const int m0 = blockIdx.x * 64;
  const int n0 = blockIdx.y * 128;
  const int K = HIDDEN;

  const int region = n0 >> 10;
  const int n_loc = n0 & 1023;
  const unsigned short* Bsel = region == 0 ? W0 : (region == 1 ? W1 : W2);
  const float* bias = region == 0 ? c0 : (region == 1 ? c1 : c2);

  const int schunk = (l & 7) ^ (l >> 3);
  const int rsw = (lo16 & 7);

  const unsigned short* pA[2];
#pragma unroll
  for (int i = 0; i < 2; ++i)
    pA[i] = A + (size_t)(m0 + w * 16 + i * 8 + (l >> 3)) * K + schunk * 8;
  const unsigned short* pB[4];
#pragma unroll
  for (int i = 0; i < 4; ++i)
    pB[i] = Bsel + (size_t)(n_loc + w * 32 + i * 8 + (l >> 3)) * K + schunk * 8;

  f32x4 acc[4][2];
#pragma unroll
  for (int mi = 0; mi < 4; ++mi)
#pragma unroll
    for (int f = 0; f < 2; ++f) acc[mi][f] = f32x4{0.f, 0.f, 0.f, 0.f};

  auto stage = [&](int BUF) __attribute__((always_inline)) {
#pragma unroll
    for (int i = 0; i < 2; ++i) {
      gll16(pA[i], &Al[BUF][(w * 16 + i * 8) * 64]);
      pA[i] += 64;
    }
#pragma unroll
    for (int i = 0; i < 4; ++i) {
      gll16(pB[i], &Bl[BUF][(w * 32 + i * 8) * 64]);
      pB[i] += 64;
    }
  };

  stage(0);
  __syncthreads();

  auto step = [&](int knext, int BUF) __attribute__((always_inline)) {
    if (knext < K) stage(BUF ^ 1);
#pragma unroll
    for (int kk = 0; kk < 2; ++kk) {
      short8 af[4], bf[2];
#pragma unroll
      for (int mi = 0; mi < 4; ++mi)
        af[mi] = *reinterpret_cast<const short8*>(
            &Al[BUF][(mi * 16 + lo16) * 64 + (((kk * 4 + hi) ^ rsw) * 8)]);
#pragma unroll
      for (int f = 0; f < 2; ++f)
        bf[f] = *reinterpret_cast<const short8*>(
            &Bl[BUF][(w * 32 + f * 16 + lo16) * 64 + (((kk * 4 + hi) ^ rsw) * 8)]);
#pragma unroll
      for (int mi = 0; mi < 4; ++mi)
#pragma unroll
        for (int f = 0; f < 2; ++f)
          acc[mi][f] =
              __builtin_amdgcn_mfma_f32_16x16x32_bf16(af[mi], bf[f], acc[mi][f], 0, 0, 0);
    }
    __syncthreads();
  };

  for (int kt = 0; kt < K; kt += 128) {
    step(kt + 64, 0);
    step(kt + 128, 1);
  }

#pragma unroll
  for (int mi = 0; mi < 4; ++mi)
#pragma unroll
    for (int f = 0; f < 2; ++f) {
      int mbase = m0 + mi * 16 + hi * 4;
      int n_rel = n_loc + w * 32 + f * 16 + lo16;
      float bv_ = bias[n_rel];
      if (region == 2) {
        // V^T: 4 consecutive s for fixed d -> one packed 8B store
        int b = mbase >> 11, s = mbase & 2047, d = n_rel & 63, h = n_rel >> 6;
        uint2 pk;
        pk.x = cvt_pk_bf16(acc[mi][f][0] + bv_, acc[mi][f][1] + bv_);
        pk.y = cvt_pk_bf16(acc[mi][f][2] + bv_, acc[mi][f][3] + bv_);
        *reinterpret_cast<uint2*>(
            (unsigned short*)o2 + ((size_t)(b * NHEAD + h) * HD + d) * SEQ + s) = pk;
        continue;
      }
#pragma unroll
      for (int j = 0; j < 4; ++j) {
        float v = acc[mi][f][j] + bv_;
        int mm = mbase + j;
        int b = mm >> 11, s = mm & 2047, h = n_rel >> 6, d = n_rel & 63;
        if (region == 0)
          ((unsigned short*)o0)[((size_t)(b * NHEAD + h) * SEQ + s) * HD + d] =
              f2b(v * QSCALE);
        else
          ((unsigned short*)o1)[((size_t)(b * NHEAD + h) * SEQ + s) * HD + d] =
              f2b(v);
      }
    }
}

// ---------------- O-projection GEMM: 64x128 tile, BK=64, 2-phase dbuf --------
__global__ __launch_bounds__(256) void gemm_o_kernel(
    const unsigned short* __restrict__ A, const unsigned short* __restrict__ W0,
    const float* __restrict__ bias, float* __restrict__ out) {
  __shared__ __align__(16) unsigned short Al[2][64 * 64];
  __shared__ __align__(16) unsigned short Bl[2][128 * 64];
  const int t = threadIdx.x;
  const int w = t >> 6, l = t & 63;
  const int hi = l >> 4, lo16 = l & 15;
  const int m0 = blockIdx.x * 64;
  const int n0 = blockIdx.y * 128;
  const int K = HIDDEN;

  const int schunk = (l & 7) ^ (l >> 3);
  const int rsw = (lo16 & 7);

  const unsigned short* pA[2];
#pragma unroll
  for (int i = 0; i < 2; ++i)
    pA[i] = A + (size_t)(m0 + w * 16 + i * 8 + (l >> 3)) * K + schunk * 8;
  const unsigned short* pB[4];
#pragma unroll
  for (int i = 0; i < 4; ++i)
    pB[i] = W0 + (size_t)(n0 + w * 32 + i * 8 + (l >> 3)) * K + schunk * 8;

  f32x4 acc[4][2];
#pragma unroll
  for (int mi = 0; mi < 4; ++mi)
#pragma unroll
    for (int f = 0; f < 2; ++f) acc[mi][f] = f32x4{0.f, 0.f, 0.f, 0.f};

  auto stage = [&](int BUF) __attribute__((always_inline)) {
#pragma unroll
    for (int i = 0; i < 2; ++i) {
      gll16(pA[i], &Al[BUF][(w * 16 + i * 8) * 64]);
      pA[i] += 64;
    }
#pragma unroll
    for (int i = 0; i < 4; ++i) {
      gll16(pB[i], &Bl[BUF][(w * 32 + i * 8) * 64]);
      pB[i] += 64;
    }
  };

  stage(0);
  __syncthreads();

  auto step = [&](int knext, int BUF) __attribute__((always_inline)) {
    if (knext < K) stage(BUF ^ 1);
#pragma unroll
    for (int kk = 0; kk < 2; ++kk) {
      short8 af[4], bf[2];
#pragma unroll
      for (int mi = 0; mi < 4; ++mi)
        af[mi] = *reinterpret_cast<const short8*>(
            &Al[BUF][(mi * 16 + lo16) * 64 + (((kk * 4 + hi) ^ rsw) * 8)]);
#pragma unroll
      for (int f = 0; f < 2; ++f)
        bf[f] = *reinterpret_cast<const short8*>(
            &Bl[BUF][(w * 32 + f * 16 + lo16) * 64 + (((kk * 4 + hi) ^ rsw) * 8)]);
#pragma unroll
      for (int mi = 0; mi < 4; ++mi)
#pragma unroll
        for (int f = 0; f < 2; ++f)
          acc[mi][f] =
              __builtin_amdgcn_mfma_f32_16x16x32_bf16(af[mi], bf[f], acc[mi][f], 0, 0, 0);
    }
    __syncthreads();
  };

  for (int kt = 0; kt < K; kt += 128) {
    step(kt + 64, 0);
    step(kt + 128, 1);
  }

#pragma unroll
  for (int mi = 0; mi < 4; ++mi)
#pragma unroll
    for (int f = 0; f < 2; ++f) {
      int mbase = m0 + mi * 16 + hi * 4;
      int n = n0 + w * 32 + f * 16 + lo16;
      float bv_ = bias[n];
#pragma unroll
      for (int j = 0; j < 4; ++j)
        out[(size_t)(mbase + j) * HIDDEN + n] = acc[mi][f][j] + bv_;
    }
}

// ---------------- flash attention: 8 waves, k-split, ring-4, 2-stage pipe ----
// (exact R18 kernel: best measured, attn ~52.3-52.6 us, conflicts 0)
__global__ __launch_bounds__(512) void attn_kernel(
    const unsigned short* __restrict__ Q, const unsigned short* __restrict__ Km,
    const unsigned short* __restrict__ Vt, const float* __restrict__ amf,
    unsigned short* __restrict__ O) {
  __shared__ __align__(16) unsigned short KV[4][2][64 * 64];  // 64 KB ring
  __shared__ float SrwS[4][64];
  const int t = threadIdx.x;
  const int w = t >> 6, l = t & 63;
  const int q31 = l & 31, hi32 = l >> 5;
  const int qg = w >> 1, half = w & 1;
  const int nb = ((blockIdx.x & 7) << 6) | (blockIdx.x >> 3);
  const int qt = nb & 15, bh = nb >> 4;
  const int b = bh >> 4, h = bh & 15;
  const int q0w = qt * 128 + qg * 32;
  const int q = q0w + q31;
  const bool diagw = (half == (qg & 1));
  const int dtile = qt * 128 + (qg >> 1) * 64;

  const unsigned short* Qb = Q + (size_t)bh * SEQ * HD;
  const unsigned short* Kb = Km + (size_t)bh * SEQ * HD;
  const unsigned short* Vb = Vt + (size_t)bh * HD * SEQ;
  const float* mb = amf + b * SEQ + half * 32;

  short8 qf[4];
#pragma unroll
  for (int dc = 0; dc < 4; ++dc)
    qf[dc] = *reinterpret_cast<const short8*>(
        Qb + (size_t)q * HD + dc * 16 + hi32 * 8);

  f32x16 o0, o1;
#pragma unroll
  for (int r = 0; r < 16; ++r) { o0[r] = 0.f; o1[r] = 0.f; }
  float srw = 0.f;

  const int srow = w * 8 + (l >> 3);
  const int sc_ = ((l & 7) ^ (l >> 3) ^ (w & 3)) * 8;
  const unsigned short* pK = Kb + (size_t)srow * HD + sc_;
  const unsigned short* pV = Vb + (size_t)srow * SEQ + sc_;

  auto stageT = [&](int BUF) __attribute__((always_inline)) {
    gll16(pK, &KV[BUF][0][(w * 8) * 64]);
    gll16(pV, &KV[BUF][1][(w * 8) * 64]);
    pK += 64 * HD; pV += 64;
  };

  stageT(0);
  stageT(1);
  stageT(2);
  asm volatile("s_waitcnt vmcnt(2)" ::: "memory");
  __builtin_amdgcn_s_barrier();
  __builtin_amdgcn_sched_barrier(0);

  const int rk = (q31 & 7) ^ (q31 >> 3);

  auto qk = [&](int k0, int BUF, f32x16& s) __attribute__((always_inline)) {
    float4 a0[4];
#pragma unroll
    for (int g = 0; g < 4; ++g)
      a0[g] = *reinterpret_cast<const float4*>(mb + k0 + g * 8 + hi32 * 4);
    if (diagw && k0 == dtile) {
      int kb = hi32 * 4;
#pragma unroll
      for (int g = 0; g < 4; ++g) {
        if (kb + g * 8 + 0 == q31) a0[g].x = 0.f;
        if (kb + g * 8 + 1 == q31) a0[g].y = 0.f;
        if (kb + g * 8 + 2 == q31) a0[g].z = 0.f;
        if (kb + g * 8 + 3 == q31) a0[g].w = 0.f;
      }
    }
#pragma unroll
    for (int g = 0; g < 4; ++g) {
      s[4 * g + 0] = a0[g].x; s[4 * g + 1] = a0[g].y;
      s[4 * g + 2] = a0[g].z; s[4 * g + 3] = a0[g].w;
    }
    __builtin_amdgcn_s_setprio(1);
#pragma unroll
    for (int dc = 0; dc < 4; ++dc) {
      short8 kf = *reinterpret_cast<const short8*>(
          &KV[BUF][0][(half * 32 + q31) * 64 + (((dc * 2 + hi32) ^ rk) * 8)]);
      s = __builtin_amdgcn_mfma_f32_32x32x16_bf16(kf, qf[dc], s, 0, 0, 0);
    }
    __builtin_amdgcn_s_setprio(0);
  };

  auto spv = [&](int BUF, f32x16& s) __attribute__((always_inline)) {
    float sum = 0.f;
#pragma unroll
    for (int r = 0; r < 16; ++r) {
      float p = fexp2(s[r]);
      s[r] = p;
      sum += p;
    }
    {
      unsigned a = __float_as_uint(sum), bsw = a;
      auto rr = __builtin_amdgcn_permlane32_swap(a, bsw, false, false);
      sum = __uint_as_float(rr[0]) + __uint_as_float(rr[1]);
    }
    srw += sum;

    unsigned c[8];
#pragma unroll
    for (int R = 0; R < 4; ++R) {
      c[R * 2 + 0] = cvt_pk_bf16(s[4 * R + 0], s[4 * R + 1]);
      c[R * 2 + 1] = cvt_pk_bf16(s[4 * R + 2], s[4 * R + 3]);
    }

    short8 pb[2];
#pragma unroll
    for (int sl = 0; sl < 2; ++sl) {
      const int R0 = sl * 2;
      auto r0 = __builtin_amdgcn_permlane32_swap(c[R0 * 2 + 0],
                                                 c[(R0 + 1) * 2 + 0], false, false);
      auto r1 = __builtin_amdgcn_permlane32_swap(c[R0 * 2 + 1],
                                                 c[(R0 + 1) * 2 + 1], false, false);
      union { unsigned u[4]; short8 s8; } pu;
      pu.u[0] = r0[0]; pu.u[1] = r1[0]; pu.u[2] = r0[1]; pu.u[3] = r1[1];
      pb[sl] = pu.s8;
    }

    __builtin_amdgcn_s_setprio(1);
#pragma unroll
    for (int sl = 0; sl < 2; ++sl) {
      int ch = (((half * 2 + sl) * 2 + hi32) ^ rk) * 8;
      short8 vf0 = *reinterpret_cast<const short8*>(&KV[BUF][1][q31 * 64 + ch]);
      short8 vf1 =
          *reinterpret_cast<const short8*>(&KV[BUF][1][(32 + q31) * 64 + ch]);
      o0 = __builtin_amdgcn_mfma_f32_32x32x16_bf16(vf0, pb[sl], o0, 0, 0, 0);
      o1 = __builtin_amdgcn_mfma_f32_32x32x16_bf16(vf1, pb[sl], o1, 0, 0, 0);
    }
    __builtin_amdgcn_s_setprio(0);
  };

  f32x16 sA, sB;
  qk(0, 0, sA);

  auto pipe = [&](int k0, int BUF, int NBUF, f32x16& scur, f32x16& snext,
                  int WAITN) __attribute__((always_inline)) {
    if (k0 + 192 < SEQ) stageT(NBUF);
    if (k0 + 64 < SEQ) qk(k0 + 64, (BUF + 1) & 3, snext);
    spv(BUF, scur);
    if (WAITN == 2)
      asm volatile("s_waitcnt vmcnt(2)" ::: "memory");
    else if (WAITN == 0)
      asm volatile("s_waitcnt vmcnt(0)" ::: "memory");
    if (WAITN >= 0) {
      __builtin_amdgcn_s_barrier();
      __builtin_amdgcn_sched_barrier(0);
    }
  };

  for (int tt = 0; tt < 28; tt += 4) {
    pipe((tt + 0) * 64, 0, 3, sA, sB, 2);
    pipe((tt + 1) * 64, 1, 0, sB, sA, 2);
    pipe((tt + 2) * 64, 2, 1, sA, sB, 2);
    pipe((tt + 3) * 64, 3, 2, sB, sA, 2);
  }
  pipe(28 * 64, 0, 3, sA, sB, 2);
  pipe(29 * 64, 1, 0, sB, sA, 0);
  pipe(30 * 64, 2, 1, sA, sB, -1);
  pipe(31 * 64, 3, 2, sB, sA, -1);

  float* obuf = (float*)&KV[0][0][0];  // 33 KB, disjoint from tiles 30/31 bufs
  if (half) {
    float* d = obuf + (qg * 64 + l) * 33;
#pragma unroll
    for (int r = 0; r < 16; ++r) { d[r] = o0[r]; d[16 + r] = o1[r]; }
    SrwS[qg][l] = srw;
  }
  __syncthreads();
  if (!half) {
    const float* d = obuf + (qg * 64 + l) * 33;
#pragma unroll
    for (int r = 0; r < 16; ++r) { o0[r] += d[r]; o1[r] += d[16 + r]; }
    srw += SrwS[qg][l];

    float rinv = 1.f / srw;
    unsigned short* Ob = O + (size_t)(b * SEQ + q) * HIDDEN + h * HD;
#pragma unroll
    for (int g = 0; g < 4; ++g) {
      uint2 w0, w1;
      w0.x = cvt_pk_bf16(o0[4 * g + 0] * rinv, o0[4 * g + 1] * rinv);
      w0.y = cvt_pk_bf16(o0[4 * g + 2] * rinv, o0[4 * g + 3] * rinv);
      w1.x = cvt_pk_bf16(o1[4 * g + 0] * rinv, o1[4 * g + 1] * rinv);
      w1.y = cvt_pk_bf16(o1[4 * g + 2] * rinv, o1[4 * g + 3] * rinv);
      *reinterpret_cast<uint2*>(Ob + 8 * g + 4 * hi32) = w0;
      *reinterpret_cast<uint2*>(Ob + 32 + 8 * g + 4 * hi32) = w1;
    }
  }
}

// ---------------- launch ----------------
extern "C" void kernel_launch(void* const* d_in, const int* in_sizes, int n_in,
                              void* d_out, int out_size, void* d_ws,
                              size_t ws_size, hipStream_t stream) {
  const float* x = (const float*)d_in[0];
  const int* mask = (const int*)d_in[1];
  const float* Wq = (const float*)d_in[2];
  const float* bq = (const float*)d_in[3];
  const float* Wk = (const float*)d_in[4];
  const float* bk = (const float*)d_in[5];
  const float* Wv = (const float*)d_in[6];
  const float* bv = (const float*)d_in[7];
  const float* Wo = (const float*)d_in[8];
  const float* bo = (const float*)d_in[9];

  char* ws = (char*)d_ws;
  unsigned short* xb  = (unsigned short*)(ws + ((size_t)0 << 20));   // 8 MB
  unsigned short* wqb = (unsigned short*)(ws + ((size_t)8 << 20));   // 2 MB
  unsigned short* wkb = (unsigned short*)(ws + ((size_t)10 << 20));
  unsigned short* wvb = (unsigned short*)(ws + ((size_t)12 << 20));
  unsigned short* wob = (unsigned short*)(ws + ((size_t)14 << 20));
  unsigned short* qw  = (unsigned short*)(ws + ((size_t)16 << 20));  // 8 MB
  unsigned short* kw  = (unsigned short*)(ws + ((size_t)24 << 20));
  unsigned short* vtw = (unsigned short*)(ws + ((size_t)32 << 20));
  unsigned short* ow  = (unsigned short*)(ws + ((size_t)40 << 20));
  // additive mask overlays xb (xb is dead after the QKV GEMM)
  float* amf = (float*)(ws + ((size_t)0 << 20));

  // all f32->bf16 conversions in one launch
  prep_kernel<<<8192, 256, 0, stream>>>(x, Wq, Wk, Wv, Wo, xb, wqb, wkb, wvb,
                                        wob);

  // fused QKV projection: [4096 x 3072], 64x128 tiles
  gemm_qkv_kernel<<<dim3(MROWS / 64, 3 * HIDDEN / 128), 256, 0, stream>>>(
      xb, wqb, wkb, wvb, bq, bk, bv, qw, kw, vtw);

  // additive mask (after QKV GEMM: overwrites start of xb region)
  amask_kernel<<<MROWS / 256, 256, 0, stream>>>(mask, amf, MROWS);

  attn_kernel<<<512, 512, 0, stream>>>(qw, kw, vtw, amf, ow);

  // output projection: [4096 x 1024] f32, 64x128 tiles
  gemm_o_kernel<<<dim3(MROWS / 64, HIDDEN / 128), 256, 0, stream>>>(
      ow, wob, bo, (float*)d_out);
}